// Round 14
// baseline (85.225 us; speedup 1.0000x reference)
//
#include <hip/hip_runtime.h>
#include <hip/hip_fp16.h>

#define NN 50000
#define NE 625000
#define D  128
#define CAP 64       // bucket capacity per node (LDS: 32*CAP*4 = 8KB per block)
#define NBIN 196     // ceil(NN/256): coarse bin = dst >> 8
#define BCAP 4096    // entries per coarse bin (mean 3189, sigma ~57)
#define BIN_BLOCKS 200
#define BIN_CHUNK 3125   // NE / BIN_BLOCKS
#define GBM 128      // GEMM rows per block
#define XC_BLKS 3125     // NN*D/8/256
#define K1_X  BIN_BLOCKS               // x-convert blocks start here
#define K1_W  (BIN_BLOCKS + XC_BLKS)   // W-split blocks start here (3325)
#define K1_GRID (K1_W + 8)             // 3333
#define LSPILL 64

typedef __attribute__((ext_vector_type(8))) short bf16x8;
typedef __attribute__((ext_vector_type(4))) float f32x4;

__device__ inline unsigned f2bf_rne(float f) {
    unsigned u = __float_as_uint(f);
    u += 0x7FFFu + ((u >> 16) & 1u);
    return u >> 16;
}

__device__ inline unsigned pack_hi(float a, float b, float& ra, float& rb) {
    unsigned ba = __float_as_uint(a) & 0xffff0000u;
    unsigned bb = __float_as_uint(b) & 0xffff0000u;
    ra = a - __uint_as_float(ba);
    rb = b - __uint_as_float(bb);
    return (ba >> 16) | bb;
}
__device__ inline unsigned pack_lo(float ra, float rb) {
    return (__float_as_uint(ra) >> 16) | (__float_as_uint(rb) & 0xffff0000u);
}

__device__ inline float hw(unsigned q) {
    return __half2float(__ushort_as_half((ushort)(q & 0xffffu)));
}

__device__ inline void edge_fma(float4& acc, uint2 u, float wt) {
    acc.x += __uint_as_float(u.x << 16) * wt;
    acc.y += __uint_as_float(u.x & 0xffff0000u) * wt;
    acc.z += __uint_as_float(u.y << 16) * wt;
    acc.w += __uint_as_float(u.y & 0xffff0000u) * wt;
}

// ---- k1: [0,200) bin_coarse | [200,3325) x->bf16 | [3325,3333) W-split ----
// requires binc[NBIN] and ovf_cnt pre-zeroed (hipMemsetAsync)
__global__ __launch_bounds__(256) void k1(const float* __restrict__ x,
                                          const float* __restrict__ W,
                                          const int* __restrict__ src,
                                          const int* __restrict__ dst,
                                          const float* __restrict__ ew,
                                          unsigned* __restrict__ xb,
                                          ushort* __restrict__ wsp,
                                          int* __restrict__ binc,
                                          uint2* __restrict__ binbuf,
                                          int* __restrict__ ovf_cnt,
                                          uint2* __restrict__ ovf) {
    const int tid = threadIdx.x;
    if (blockIdx.x < K1_X) {
        // ---- coarse binning, per-wave slot counters ----
        __shared__ int hcnt[4][NBIN];
        __shared__ int hbase4[4][NBIN];
        __shared__ int hcur4[4][NBIN];
        const int wv = tid >> 6;
        const int e0 = blockIdx.x * BIN_CHUNK;
        const int e1 = min(e0 + BIN_CHUNK, NE);
        for (int i = tid; i < NBIN; i += 256) {
            hcnt[0][i] = 0; hcnt[1][i] = 0; hcnt[2][i] = 0; hcnt[3][i] = 0;
        }
        __syncthreads();
        for (int e = e0 + tid; e < e1; e += 256)
            atomicAdd(&hcnt[wv][dst[e] >> 8], 1);
        __syncthreads();
        for (int i = tid; i < NBIN; i += 256) {
            int c0 = hcnt[0][i], c1 = hcnt[1][i], c2 = hcnt[2][i], c3 = hcnt[3][i];
            int tot = c0 + c1 + c2 + c3;
            int base = tot ? atomicAdd(&binc[i], tot) : 0;
            hbase4[0][i] = base;
            hbase4[1][i] = base + c0;
            hbase4[2][i] = base + c0 + c1;
            hbase4[3][i] = base + c0 + c1 + c2;
            hcur4[0][i] = 0; hcur4[1][i] = 0; hcur4[2][i] = 0; hcur4[3][i] = 0;
        }
        __syncthreads();
        for (int e = e0 + tid; e < e1; e += 256) {
            int d = dst[e];
            int bin = d >> 8;
            unsigned entry = ((unsigned)src[e] << 16) |
                             (unsigned)__half_as_ushort(__float2half(ew[e]));
            int slot = hbase4[wv][bin] + atomicAdd(&hcur4[wv][bin], 1);
            if (slot < BCAP) {
                binbuf[(size_t)bin * BCAP + slot] = make_uint2((unsigned)d, entry);
            } else {
                int o = atomicAdd(ovf_cnt, 1);
                ovf[o] = make_uint2((unsigned)d, entry);
            }
        }
        return;
    }
    if (blockIdx.x < K1_W) {
        // ---- x -> bf16 ----
        int g = (blockIdx.x - K1_X) * 256 + tid;
        const float4* xp = (const float4*)(x + (size_t)g * 8);
        float4 a = xp[0], b = xp[1];
        uint4 o;
        o.x = f2bf_rne(a.x) | (f2bf_rne(a.y) << 16);
        o.y = f2bf_rne(a.z) | (f2bf_rne(a.w) << 16);
        o.z = f2bf_rne(b.x) | (f2bf_rne(b.y) << 16);
        o.w = f2bf_rne(b.z) | (f2bf_rne(b.w) << 16);
        ((uint4*)xb)[g] = o;
        return;
    }
    // ---- W split (pre-swizzled) ----
    int g = (blockIdx.x - K1_W) * 256 + tid;
    if (g >= 128 * 16) return;
    int col = g >> 4;
    int c16 = g & 15;
    const float4* wp = (const float4*)(W + (size_t)col * D + c16 * 8);
    float4 v0 = wp[0], v1 = wp[1];
    float r0, r1, r2, r3, r4, r5, r6, r7;
    uint4 hi, lo;
    hi.x = pack_hi(v0.x, v0.y, r0, r1);
    hi.y = pack_hi(v0.z, v0.w, r2, r3);
    hi.z = pack_hi(v1.x, v1.y, r4, r5);
    hi.w = pack_hi(v1.z, v1.w, r6, r7);
    lo.x = pack_lo(r0, r1); lo.y = pack_lo(r2, r3);
    lo.z = pack_lo(r4, r5); lo.w = pack_lo(r6, r7);
    int sidx = col * 16 + (c16 ^ (col & 15));
    ((uint4*)wsp)[sidx] = hi;
    ((uint4*)(wsp + 16384))[sidx] = lo;
}

// ---- k2 bin_scan_agg: 8 sub-blocks per bin, each owns 32 nodes ----
// scan the bin's entries (redundant 8x, L2-hot), LDS-scatter own nodes,
// then aggregate from LDS with 16 gathers in flight; write bf16 aggb.
__global__ __launch_bounds__(256) void bin_scan_agg(const int* __restrict__ binc,
                                                    const uint2* __restrict__ binbuf,
                                                    const unsigned* __restrict__ xb,
                                                    const int* __restrict__ ovf_cnt,
                                                    const uint2* __restrict__ ovf,
                                                    unsigned* __restrict__ aggb) {
    __shared__ unsigned lbuck[32 * CAP];   // 8KB
    __shared__ int lcnt[32];
    __shared__ uint2 lspill[LSPILL];
    __shared__ int lspill_n;
    const int tid = threadIdx.x;
    const int bin = blockIdx.x >> 3;
    const int sub = blockIdx.x & 7;        // owns lidx [sub*32, sub*32+32)
    {
        uint2* lb2 = (uint2*)lbuck;
#pragma unroll
        for (int i = 0; i < 4; ++i)
            lb2[i * 256 + tid] = make_uint2(0u, 0u);
        if (tid < 32) lcnt[tid] = 0;
        if (tid == 0) lspill_n = 0;
    }
    __syncthreads();
    int n = binc[bin];
    if (n > BCAP) n = BCAP;
    const uint2* bp = binbuf + (size_t)bin * BCAP;
    for (int i = tid; i < n; i += 256) {
        uint2 q = bp[i];
        int lidx = (int)(q.x & 255u);
        if ((lidx >> 5) != sub) continue;
        int l5 = lidx & 31;
        int p = atomicAdd(&lcnt[l5], 1);
        if (p < CAP) {
            lbuck[l5 * CAP + p] = q.y;
        } else {
            int s = atomicAdd(&lspill_n, 1);
            if (s < LSPILL) lspill[s] = q;   // deg>CAP+LSPILL impossible (deg<=... Poisson)
        }
    }
    __syncthreads();
    const int hwv = tid >> 5;    // half-wave 0..7
    const int t = tid & 31;      // lane owns dims 4t..4t+3
    const uint2* x2 = (const uint2*)xb;
    const int nsp = min(lspill_n, LSPILL);
    const int novf = *ovf_cnt;   // k1 BCAP spills (written in prior kernel)
#pragma unroll
    for (int j = 0; j < 4; ++j) {
        int l5 = hwv * 4 + j;
        int node = bin * 256 + sub * 32 + l5;
        if (node >= NN) continue;
        int c = lcnt[l5];
        if (c > CAP) c = CAP;
        float4 acc = {0.f, 0.f, 0.f, 0.f};
        const uint4* lb4 = (const uint4*)(lbuck + l5 * CAP);
        int rounds = (c + 15) >> 4;          // slots beyond c are zero (w=+0)
        for (int r = 0; r < rounds; ++r) {
            uint4 q0 = lb4[r * 4 + 0], q1 = lb4[r * 4 + 1];
            uint4 q2 = lb4[r * 4 + 2], q3 = lb4[r * 4 + 3];
            uint2 u00 = x2[(size_t)(q0.x >> 16) * 32 + t];
            uint2 u01 = x2[(size_t)(q0.y >> 16) * 32 + t];
            uint2 u02 = x2[(size_t)(q0.z >> 16) * 32 + t];
            uint2 u03 = x2[(size_t)(q0.w >> 16) * 32 + t];
            uint2 u10 = x2[(size_t)(q1.x >> 16) * 32 + t];
            uint2 u11 = x2[(size_t)(q1.y >> 16) * 32 + t];
            uint2 u12 = x2[(size_t)(q1.z >> 16) * 32 + t];
            uint2 u13 = x2[(size_t)(q1.w >> 16) * 32 + t];
            uint2 u20 = x2[(size_t)(q2.x >> 16) * 32 + t];
            uint2 u21 = x2[(size_t)(q2.y >> 16) * 32 + t];
            uint2 u22 = x2[(size_t)(q2.z >> 16) * 32 + t];
            uint2 u23 = x2[(size_t)(q2.w >> 16) * 32 + t];
            uint2 u30 = x2[(size_t)(q3.x >> 16) * 32 + t];
            uint2 u31 = x2[(size_t)(q3.y >> 16) * 32 + t];
            uint2 u32 = x2[(size_t)(q3.z >> 16) * 32 + t];
            uint2 u33 = x2[(size_t)(q3.w >> 16) * 32 + t];
            edge_fma(acc, u00, hw(q0.x)); edge_fma(acc, u01, hw(q0.y));
            edge_fma(acc, u02, hw(q0.z)); edge_fma(acc, u03, hw(q0.w));
            edge_fma(acc, u10, hw(q1.x)); edge_fma(acc, u11, hw(q1.y));
            edge_fma(acc, u12, hw(q1.z)); edge_fma(acc, u13, hw(q1.w));
            edge_fma(acc, u20, hw(q2.x)); edge_fma(acc, u21, hw(q2.y));
            edge_fma(acc, u22, hw(q2.z)); edge_fma(acc, u23, hw(q2.w));
            edge_fma(acc, u30, hw(q3.x)); edge_fma(acc, u31, hw(q3.y));
            edge_fma(acc, u32, hw(q3.z)); edge_fma(acc, u33, hw(q3.w));
        }
        int lidx = sub * 32 + l5;
        for (int s = 0; s < nsp; ++s) {      // statistically never
            uint2 q = lspill[s];
            if ((int)(q.x & 255u) == lidx) {
                uint2 u = x2[(size_t)(q.y >> 16) * 32 + t];
                edge_fma(acc, u, hw(q.y));
            }
        }
        for (int o = 0; o < novf; ++o) {     // statistically never
            uint2 q = ovf[o];
            if ((int)q.x == node) {
                uint2 u = x2[(size_t)(q.y >> 16) * 32 + t];
                edge_fma(acc, u, hw(q.y));
            }
        }
        unsigned o0 = f2bf_rne(acc.x) | (f2bf_rne(acc.y) << 16);
        unsigned o1 = f2bf_rne(acc.z) | (f2bf_rne(acc.w) << 16);
        ((uint2*)aggb)[(size_t)node * 32 + t] = make_uint2(o0, o1);
    }
}

// ---- k3 GEMM: bf16 A direct, W hi+lo split, bias+relu ----
__global__ __launch_bounds__(256) void gemm_mfma(const unsigned* __restrict__ aggb,
                                                 const ushort* __restrict__ wsp,
                                                 const float* __restrict__ bias,
                                                 float* __restrict__ out) {
    __shared__ ushort wl[32768];
    const int tid = threadIdx.x;
    {
        const uint4* s = (const uint4*)wsp;
        uint4* d = (uint4*)wl;
#pragma unroll
        for (int i = 0; i < 16; ++i)
            d[i * 256 + tid] = s[i * 256 + tid];
    }
    __syncthreads();

    const int wid = tid >> 6, lane = tid & 63;
    const int l15 = lane & 15, kg = lane >> 4;
    const int wrbase = blockIdx.x * GBM + wid * 32;

    f32x4 acc[2][8];
    const f32x4 fz = {0.f, 0.f, 0.f, 0.f};
#pragma unroll
    for (int m = 0; m < 2; ++m)
#pragma unroll
        for (int n = 0; n < 8; ++n) acc[m][n] = fz;

    int arow0 = wrbase + l15;
    int arow1 = wrbase + 16 + l15;
    const unsigned* a0p = aggb + (size_t)(arow0 < NN ? arow0 : NN - 1) * 64 + kg * 4;
    const unsigned* a1p = aggb + (size_t)(arow1 < NN ? arow1 : NN - 1) * 64 + kg * 4;

#pragma unroll
    for (int kk = 0; kk < 4; ++kk) {
        uint4 h0 = *(const uint4*)(a0p + kk * 16);
        uint4 h1 = *(const uint4*)(a1p + kk * 16);
        bf16x8 a0 = *(bf16x8*)&h0;
        bf16x8 a1 = *(bf16x8*)&h1;

        int coff = ((kk * 4 + kg) ^ l15) * 8;
#pragma unroll
        for (int nf = 0; nf < 8; ++nf) {
            int bidx = (16 * nf + l15) * 128 + coff;
            bf16x8 bhi = *(const bf16x8*)&wl[bidx];
            bf16x8 blo = *(const bf16x8*)&wl[16384 + bidx];
            acc[0][nf] = __builtin_amdgcn_mfma_f32_16x16x32_bf16(a0, bhi, acc[0][nf], 0, 0, 0);
            acc[1][nf] = __builtin_amdgcn_mfma_f32_16x16x32_bf16(a1, bhi, acc[1][nf], 0, 0, 0);
            acc[0][nf] = __builtin_amdgcn_mfma_f32_16x16x32_bf16(a0, blo, acc[0][nf], 0, 0, 0);
            acc[1][nf] = __builtin_amdgcn_mfma_f32_16x16x32_bf16(a1, blo, acc[1][nf], 0, 0, 0);
        }
    }

    const int rofs = kg * 4;
#pragma unroll
    for (int nf = 0; nf < 8; ++nf) {
        int col = 16 * nf + l15;
        float bv = bias[col];
#pragma unroll
        for (int m = 0; m < 2; ++m) {
#pragma unroll
            for (int r = 0; r < 4; ++r) {
                int row = wrbase + 16 * m + rofs + r;
                if (row < NN) {
                    float h = acc[m][nf][r] + bv;
                    out[(size_t)row * D + col] = h > 0.f ? h : 0.f;
                }
            }
        }
    }
}

extern "C" void kernel_launch(void* const* d_in, const int* in_sizes, int n_in,
                              void* d_out, int out_size, void* d_ws, size_t ws_size,
                              hipStream_t stream) {
    const float* x    = (const float*)d_in[0];
    const int*   eidx = (const int*)d_in[1];   // [2, E] flat: src then dst
    const float* ew   = (const float*)d_in[2];
    const float* W    = (const float*)d_in[3];
    const float* bias = (const float*)d_in[4];
    float* out = (float*)d_out;

    const int* src = eidx;
    const int* dst = eidx + NE;

    // workspace layout — NO aliasing (bin_scan_agg reads binbuf while writing aggb)
    char* base = (char*)d_ws;
    unsigned* aggb   = (unsigned*)base;                         // 12.8 MB
    uint2*    binbuf = (uint2*)(base + 12800000);               // 196*4096*8 = 6.42 MB
    unsigned* xb     = (unsigned*)(base + 19300000);            // 12.8 MB
    ushort*   wsp    = (ushort*)(base + 32100000);              // 64 KB
    int*      binc    = (int*)(base + 32200000);                // 784 B
    int*      ovf_cnt = (int*)((char*)binc + NBIN * 4);         // adjacent: one memset
    uint2*    ovf     = (uint2*)(base + 32201024);              // 512 KB

    hipMemsetAsync(binc, 0, NBIN * 4 + 4, stream);
    k1<<<K1_GRID, 256, 0, stream>>>(x, W, src, dst, ew, xb, wsp, binc, binbuf, ovf_cnt, ovf);
    bin_scan_agg<<<NBIN * 8, 256, 0, stream>>>(binc, binbuf, xb, ovf_cnt, ovf, aggb);
    gemm_mfma<<<(NN + GBM - 1) / GBM, 256, 0, stream>>>(aggb, wsp, bias, out);
}

// Round 16
// 82.257 us; speedup vs baseline: 1.0361x; 1.0361x over previous
//
#include <hip/hip_runtime.h>
#include <hip/hip_fp16.h>

#define NN 50000
#define NE 625000
#define D  128
#define CAP 64       // bucket capacity per node
#define NBIN 196     // ceil(NN/256): coarse bin = dst >> 8
#define BCAP 4096    // entries per coarse bin (mean 3189, sigma ~57)
#define BIN_BLOCKS 400
#define BIN_CHUNK 1563   // ceil(NE / BIN_BLOCKS)
#define GBM 128      // GEMM rows per block
#define XC_BLKS 3125     // NN*D/8/256
#define K1_X  BIN_BLOCKS               // x-convert blocks start here
#define K1_W  (BIN_BLOCKS + XC_BLKS)   // W-split blocks start here
#define K1_GRID (K1_W + 8)

typedef __attribute__((ext_vector_type(8))) short bf16x8;
typedef __attribute__((ext_vector_type(4))) float f32x4;

__device__ inline unsigned f2bf_rne(float f) {
    unsigned u = __float_as_uint(f);
    u += 0x7FFFu + ((u >> 16) & 1u);
    return u >> 16;
}

__device__ inline unsigned pack_hi(float a, float b, float& ra, float& rb) {
    unsigned ba = __float_as_uint(a) & 0xffff0000u;
    unsigned bb = __float_as_uint(b) & 0xffff0000u;
    ra = a - __uint_as_float(ba);
    rb = b - __uint_as_float(bb);
    return (ba >> 16) | bb;
}
__device__ inline unsigned pack_lo(float ra, float rb) {
    return (__float_as_uint(ra) >> 16) | (__float_as_uint(rb) & 0xffff0000u);
}

__device__ inline float hw(unsigned q) {
    return __half2float(__ushort_as_half((ushort)(q & 0xffffu)));
}

__device__ inline void edge_fma(float4& acc, uint2 u, float wt) {
    acc.x += __uint_as_float(u.x << 16) * wt;
    acc.y += __uint_as_float(u.x & 0xffff0000u) * wt;
    acc.z += __uint_as_float(u.y << 16) * wt;
    acc.w += __uint_as_float(u.y & 0xffff0000u) * wt;
}

// ---- k1: [0,400) bin_coarse | [400,3525) x->bf16 | [3525,3533) W-split ----
// requires binc[NBIN] and ovf_cnt pre-zeroed (hipMemsetAsync)
__global__ __launch_bounds__(256) void k1(const float* __restrict__ x,
                                          const float* __restrict__ W,
                                          const int* __restrict__ src,
                                          const int* __restrict__ dst,
                                          const float* __restrict__ ew,
                                          unsigned* __restrict__ xb,
                                          ushort* __restrict__ wsp,
                                          int* __restrict__ binc,
                                          uint2* __restrict__ binbuf,
                                          int* __restrict__ ovf_cnt,
                                          uint2* __restrict__ ovf) {
    const int tid = threadIdx.x;
    if (blockIdx.x < K1_X) {
        // ---- coarse binning, per-wave slot counters ----
        __shared__ int hcnt[4][NBIN];
        __shared__ int hbase4[4][NBIN];
        __shared__ int hcur4[4][NBIN];
        const int wv = tid >> 6;
        const int e0 = blockIdx.x * BIN_CHUNK;
        const int e1 = min(e0 + BIN_CHUNK, NE);
        for (int i = tid; i < NBIN; i += 256) {
            hcnt[0][i] = 0; hcnt[1][i] = 0; hcnt[2][i] = 0; hcnt[3][i] = 0;
        }
        __syncthreads();
        for (int e = e0 + tid; e < e1; e += 256)
            atomicAdd(&hcnt[wv][dst[e] >> 8], 1);
        __syncthreads();
        for (int i = tid; i < NBIN; i += 256) {
            int c0 = hcnt[0][i], c1 = hcnt[1][i], c2 = hcnt[2][i], c3 = hcnt[3][i];
            int tot = c0 + c1 + c2 + c3;
            int base = tot ? atomicAdd(&binc[i], tot) : 0;
            hbase4[0][i] = base;
            hbase4[1][i] = base + c0;
            hbase4[2][i] = base + c0 + c1;
            hbase4[3][i] = base + c0 + c1 + c2;
            hcur4[0][i] = 0; hcur4[1][i] = 0; hcur4[2][i] = 0; hcur4[3][i] = 0;
        }
        __syncthreads();
        for (int e = e0 + tid; e < e1; e += 256) {
            int d = dst[e];
            int bin = d >> 8;
            unsigned entry = ((unsigned)src[e] << 16) |
                             (unsigned)__half_as_ushort(__float2half(ew[e]));
            int slot = hbase4[wv][bin] + atomicAdd(&hcur4[wv][bin], 1);
            if (slot < BCAP) {
                binbuf[(size_t)bin * BCAP + slot] = make_uint2((unsigned)d, entry);
            } else {
                int o = atomicAdd(ovf_cnt, 1);
                ovf[o] = make_uint2((unsigned)d, entry);
            }
        }
        return;
    }
    if (blockIdx.x < K1_W) {
        // ---- x -> bf16 ----
        int g = (blockIdx.x - K1_X) * 256 + tid;
        const float4* xp = (const float4*)(x + (size_t)g * 8);
        float4 a = xp[0], b = xp[1];
        uint4 o;
        o.x = f2bf_rne(a.x) | (f2bf_rne(a.y) << 16);
        o.y = f2bf_rne(a.z) | (f2bf_rne(a.w) << 16);
        o.z = f2bf_rne(b.x) | (f2bf_rne(b.y) << 16);
        o.w = f2bf_rne(b.z) | (f2bf_rne(b.w) << 16);
        ((uint4*)xb)[g] = o;
        return;
    }
    // ---- W split (pre-swizzled) ----
    int g = (blockIdx.x - K1_W) * 256 + tid;
    if (g >= 128 * 16) return;
    int col = g >> 4;
    int c16 = g & 15;
    const float4* wp = (const float4*)(W + (size_t)col * D + c16 * 8);
    float4 v0 = wp[0], v1 = wp[1];
    float r0, r1, r2, r3, r4, r5, r6, r7;
    uint4 hi, lo;
    hi.x = pack_hi(v0.x, v0.y, r0, r1);
    hi.y = pack_hi(v0.z, v0.w, r2, r3);
    hi.z = pack_hi(v1.x, v1.y, r4, r5);
    hi.w = pack_hi(v1.z, v1.w, r6, r7);
    lo.x = pack_lo(r0, r1); lo.y = pack_lo(r2, r3);
    lo.z = pack_lo(r4, r5); lo.w = pack_lo(r6, r7);
    int sidx = col * 16 + (c16 ^ (col & 15));
    ((uint4*)wsp)[sidx] = hi;
    ((uint4*)(wsp + 16384))[sidx] = lo;
}

// ---- k2 bin_fill: per-bin scatter into node buckets; pad to multiple of 8 ----
__global__ __launch_bounds__(256) void bin_fill(const int* __restrict__ binc,
                                                const uint2* __restrict__ binbuf,
                                                int* __restrict__ fillc,
                                                unsigned* __restrict__ buck,
                                                int* __restrict__ ovf_cnt,
                                                uint2* __restrict__ ovf) {
    __shared__ int lcnt[256];
    const int tid = threadIdx.x;
    const int bin = blockIdx.x;
    lcnt[tid] = 0;
    __syncthreads();
    int n = binc[bin];
    if (n > BCAP) n = BCAP;
    const uint2* bp = binbuf + (size_t)bin * BCAP;
    for (int i = tid; i < n; i += 256) {
        uint2 q = bp[i];
        int d = (int)q.x;
        int p = atomicAdd(&lcnt[d & 255], 1);
        if (p < CAP) {
            buck[(size_t)d * CAP + p] = q.y;
        } else {
            int o = atomicAdd(ovf_cnt, 1);
            ovf[o] = q;
        }
    }
    __syncthreads();
    int node = bin * 256 + tid;
    if (node < NN) {
        int c = lcnt[tid];
        if (c > CAP) c = CAP;
        int pc = (c + 7) & ~7;
        if (pc == 0) pc = 8;
        for (int p = c; p < pc; ++p)
            buck[(size_t)node * CAP + p] = 0;   // src=0, w=+0.0h
        fillc[node] = pc;
    }
}

// ---- k3 aggregate: half-wave per node; 8 gathers in flight; <=64 VGPR ----
__global__ __launch_bounds__(256, 8) void aggregate(const unsigned* __restrict__ xb,
                                                    const int* __restrict__ fillc,
                                                    const unsigned* __restrict__ buck,
                                                    const int* __restrict__ ovf_cnt,
                                                    const uint2* __restrict__ ovf,
                                                    unsigned* __restrict__ aggb) {
    const int node = blockIdx.x * 8 + (threadIdx.x >> 5);
    const int t = threadIdx.x & 31;
    int cnt = fillc[node];                 // multiple of 8, >=8, <= CAP
    const uint4* bp4 = (const uint4*)(buck + (size_t)node * CAP);
    const uint2* x2 = (const uint2*)xb;
    float4 acc = {0.f, 0.f, 0.f, 0.f};
    int n8 = cnt >> 3;
    for (int i = 0; i < n8; ++i) {
        uint4 q0 = bp4[i * 2], q1 = bp4[i * 2 + 1];
        uint2 u0 = x2[(size_t)(q0.x >> 16) * 32 + t];
        uint2 u1 = x2[(size_t)(q0.y >> 16) * 32 + t];
        uint2 u2 = x2[(size_t)(q0.z >> 16) * 32 + t];
        uint2 u3 = x2[(size_t)(q0.w >> 16) * 32 + t];
        uint2 u4 = x2[(size_t)(q1.x >> 16) * 32 + t];
        uint2 u5 = x2[(size_t)(q1.y >> 16) * 32 + t];
        uint2 u6 = x2[(size_t)(q1.z >> 16) * 32 + t];
        uint2 u7 = x2[(size_t)(q1.w >> 16) * 32 + t];
        edge_fma(acc, u0, hw(q0.x)); edge_fma(acc, u1, hw(q0.y));
        edge_fma(acc, u2, hw(q0.z)); edge_fma(acc, u3, hw(q0.w));
        edge_fma(acc, u4, hw(q1.x)); edge_fma(acc, u5, hw(q1.y));
        edge_fma(acc, u6, hw(q1.z)); edge_fma(acc, u7, hw(q1.w));
    }
    // overflow entries (statistically never; correctness net)
    int n = *ovf_cnt;
    for (int o = 0; o < n; ++o) {
        uint2 q = ovf[o];
        if ((int)q.x == node) {
            uint2 u = x2[(size_t)(q.y >> 16) * 32 + t];
            edge_fma(acc, u, hw(q.y));
        }
    }
    unsigned o0 = f2bf_rne(acc.x) | (f2bf_rne(acc.y) << 16);
    unsigned o1 = f2bf_rne(acc.z) | (f2bf_rne(acc.w) << 16);
    ((uint2*)aggb)[(size_t)node * 32 + t] = make_uint2(o0, o1);
}

// ---- k4 GEMM: bf16 A direct, W hi+lo split, bias+relu ----
__global__ __launch_bounds__(256) void gemm_mfma(const unsigned* __restrict__ aggb,
                                                 const ushort* __restrict__ wsp,
                                                 const float* __restrict__ bias,
                                                 float* __restrict__ out) {
    __shared__ ushort wl[32768];
    const int tid = threadIdx.x;
    {
        const uint4* s = (const uint4*)wsp;
        uint4* d = (uint4*)wl;
#pragma unroll
        for (int i = 0; i < 16; ++i)
            d[i * 256 + tid] = s[i * 256 + tid];
    }
    __syncthreads();

    const int wid = tid >> 6, lane = tid & 63;
    const int l15 = lane & 15, kg = lane >> 4;
    const int wrbase = blockIdx.x * GBM + wid * 32;

    f32x4 acc[2][8];
    const f32x4 fz = {0.f, 0.f, 0.f, 0.f};
#pragma unroll
    for (int m = 0; m < 2; ++m)
#pragma unroll
        for (int n = 0; n < 8; ++n) acc[m][n] = fz;

    int arow0 = wrbase + l15;
    int arow1 = wrbase + 16 + l15;
    const unsigned* a0p = aggb + (size_t)(arow0 < NN ? arow0 : NN - 1) * 64 + kg * 4;
    const unsigned* a1p = aggb + (size_t)(arow1 < NN ? arow1 : NN - 1) * 64 + kg * 4;

#pragma unroll
    for (int kk = 0; kk < 4; ++kk) {
        uint4 h0 = *(const uint4*)(a0p + kk * 16);
        uint4 h1 = *(const uint4*)(a1p + kk * 16);
        bf16x8 a0 = *(bf16x8*)&h0;
        bf16x8 a1 = *(bf16x8*)&h1;

        int coff = ((kk * 4 + kg) ^ l15) * 8;
#pragma unroll
        for (int nf = 0; nf < 8; ++nf) {
            int bidx = (16 * nf + l15) * 128 + coff;
            bf16x8 bhi = *(const bf16x8*)&wl[bidx];
            bf16x8 blo = *(const bf16x8*)&wl[16384 + bidx];
            acc[0][nf] = __builtin_amdgcn_mfma_f32_16x16x32_bf16(a0, bhi, acc[0][nf], 0, 0, 0);
            acc[1][nf] = __builtin_amdgcn_mfma_f32_16x16x32_bf16(a1, bhi, acc[1][nf], 0, 0, 0);
            acc[0][nf] = __builtin_amdgcn_mfma_f32_16x16x32_bf16(a0, blo, acc[0][nf], 0, 0, 0);
            acc[1][nf] = __builtin_amdgcn_mfma_f32_16x16x32_bf16(a1, blo, acc[1][nf], 0, 0, 0);
        }
    }

    const int rofs = kg * 4;
#pragma unroll
    for (int nf = 0; nf < 8; ++nf) {
        int col = 16 * nf + l15;
        float bv = bias[col];
#pragma unroll
        for (int m = 0; m < 2; ++m) {
#pragma unroll
            for (int r = 0; r < 4; ++r) {
                int row = wrbase + 16 * m + rofs + r;
                if (row < NN) {
                    float h = acc[m][nf][r] + bv;
                    out[(size_t)row * D + col] = h > 0.f ? h : 0.f;
                }
            }
        }
    }
}

extern "C" void kernel_launch(void* const* d_in, const int* in_sizes, int n_in,
                              void* d_out, int out_size, void* d_ws, size_t ws_size,
                              hipStream_t stream) {
    const float* x    = (const float*)d_in[0];
    const int*   eidx = (const int*)d_in[1];   // [2, E] flat: src then dst
    const float* ew   = (const float*)d_in[2];
    const float* W    = (const float*)d_in[3];
    const float* bias = (const float*)d_in[4];
    float* out = (float*)d_out;

    const int* src = eidx;
    const int* dst = eidx + NE;

    // workspace layout (binbuf aliases aggb region: binbuf dead before aggregate writes)
    char* base = (char*)d_ws;
    unsigned* aggb   = (unsigned*)base;                         // NN*D bf16 = 12.8 MB
    uint2*    binbuf = (uint2*)base;                            // 6.4 MB (alias, dead first)
    unsigned* buck   = (unsigned*)(base + 25600000);            // NN*CAP*4 = 12.8 MB
    unsigned* xb     = (unsigned*)(base + 25600000 + 12800000); // 12.8 MB
    ushort*   wsp    = (ushort*)(base + 51200000);              // 64 KB
    int*      fillc   = (int*)(base + 51200000 + 65536);        // 200 KB
    int*      binc    = (int*)(base + 51200000 + 65536 + 200000);
    int*      ovf_cnt = (int*)((char*)binc + NBIN * 4);
    uint2*    ovf     = (uint2*)(base + 51200000 + 65536 + 200000 + 1024); // 512 KB

    hipMemsetAsync(binc, 0, NBIN * 4 + 4, stream);
    k1<<<K1_GRID, 256, 0, stream>>>(x, W, src, dst, ew, xb, wsp, binc, binbuf, ovf_cnt, ovf);
    bin_fill<<<NBIN, 256, 0, stream>>>(binc, binbuf, fillc, buck, ovf_cnt, ovf);
    aggregate<<<6250, 256, 0, stream>>>(xb, fillc, buck, ovf_cnt, ovf, aggb);
    gemm_mfma<<<(NN + GBM - 1) / GBM, 256, 0, stream>>>(aggb, wsp, bias, out);
}

// Round 17
// 79.713 us; speedup vs baseline: 1.0692x; 1.0319x over previous
//
#include <hip/hip_runtime.h>
#include <hip/hip_fp16.h>

#define NN 50000
#define NE 625000
#define D  128
#define CAP 64       // bucket capacity per node
#define NBIN 196     // ceil(NN/256): coarse bin = dst >> 8
#define BCAP 4096    // entries per coarse bin (mean 3189, sigma ~57)
#define BIN_BLOCKS 200
#define BIN_CHUNK 3125   // NE / BIN_BLOCKS
#define GBM 128      // GEMM rows per block
#define PREP_BLKS 3125   // NN*D/8/256
#define MEGA_X  BIN_BLOCKS
#define MEGA_W  (BIN_BLOCKS + PREP_BLKS)
#define MEGA_GRID (MEGA_W + 8)

typedef __attribute__((ext_vector_type(8))) short bf16x8;
typedef __attribute__((ext_vector_type(4))) float f32x4;

__device__ inline unsigned f2bf_rne(float f) {
    unsigned u = __float_as_uint(f);
    u += 0x7FFFu + ((u >> 16) & 1u);
    return u >> 16;
}

// ---- W split helpers (fp32 -> bf16 hi + residual lo), pre-swizzled ----
__device__ inline unsigned pack_hi(float a, float b, float& ra, float& rb) {
    unsigned ba = __float_as_uint(a) & 0xffff0000u;
    unsigned bb = __float_as_uint(b) & 0xffff0000u;
    ra = a - __uint_as_float(ba);
    rb = b - __uint_as_float(bb);
    return (ba >> 16) | bb;
}
__device__ inline unsigned pack_lo(float ra, float rb) {
    return (__float_as_uint(ra) >> 16) | (__float_as_uint(rb) & 0xffff0000u);
}

// ---- mega1: [0,200) bin_coarse | [200,3325) x->bf16 | [3325,3333) W-split ----
__global__ __launch_bounds__(256) void mega1(const float* __restrict__ x,
                                             const float* __restrict__ W,
                                             const int* __restrict__ src,
                                             const int* __restrict__ dst,
                                             const float* __restrict__ ew,
                                             unsigned* __restrict__ xb,
                                             ushort* __restrict__ wsp,
                                             int* __restrict__ binc,
                                             uint2* __restrict__ binbuf,
                                             int* __restrict__ ovf_cnt,
                                             uint2* __restrict__ ovf) {
    const int tid = threadIdx.x;
    if (blockIdx.x < MEGA_X) {
        __shared__ int hcnt[4][NBIN];
        __shared__ int hbase[NBIN];
        __shared__ int hcur[NBIN];
        const int wv = tid >> 6;
        const int e0 = blockIdx.x * BIN_CHUNK;
        const int e1 = min(e0 + BIN_CHUNK, NE);
        for (int i = tid; i < NBIN; i += 256) {
            hcnt[0][i] = 0; hcnt[1][i] = 0; hcnt[2][i] = 0; hcnt[3][i] = 0;
        }
        __syncthreads();
        for (int e = e0 + tid; e < e1; e += 256)
            atomicAdd(&hcnt[wv][dst[e] >> 8], 1);
        __syncthreads();
        for (int i = tid; i < NBIN; i += 256) {
            int c = hcnt[0][i] + hcnt[1][i] + hcnt[2][i] + hcnt[3][i];
            hbase[i] = c ? atomicAdd(&binc[i], c) : 0;
            hcur[i] = 0;
        }
        __syncthreads();
        for (int e = e0 + tid; e < e1; e += 256) {
            int d = dst[e];
            int bin = d >> 8;
            unsigned entry = ((unsigned)src[e] << 16) |
                             (unsigned)__half_as_ushort(__float2half(ew[e]));
            int slot = hbase[bin] + atomicAdd(&hcur[bin], 1);
            if (slot < BCAP) {
                binbuf[(size_t)bin * BCAP + slot] = make_uint2((unsigned)d, entry);
            } else {
                int o = atomicAdd(ovf_cnt, 1);
                ovf[o] = make_uint2((unsigned)d, entry);
            }
        }
        return;
    }
    if (blockIdx.x < MEGA_W) {
        int g = (blockIdx.x - MEGA_X) * 256 + tid;
        const float4* xp = (const float4*)(x + (size_t)g * 8);
        float4 a = xp[0], b = xp[1];
        uint4 o;
        o.x = f2bf_rne(a.x) | (f2bf_rne(a.y) << 16);
        o.y = f2bf_rne(a.z) | (f2bf_rne(a.w) << 16);
        o.z = f2bf_rne(b.x) | (f2bf_rne(b.y) << 16);
        o.w = f2bf_rne(b.z) | (f2bf_rne(b.w) << 16);
        ((uint4*)xb)[g] = o;
        return;
    }
    int g = (blockIdx.x - MEGA_W) * 256 + tid;
    if (g >= 128 * 16) return;
    int col = g >> 4;
    int c16 = g & 15;
    const float4* wp = (const float4*)(W + (size_t)col * D + c16 * 8);
    float4 v0 = wp[0], v1 = wp[1];
    float r0, r1, r2, r3, r4, r5, r6, r7;
    uint4 hi, lo;
    hi.x = pack_hi(v0.x, v0.y, r0, r1);
    hi.y = pack_hi(v0.z, v0.w, r2, r3);
    hi.z = pack_hi(v1.x, v1.y, r4, r5);
    hi.w = pack_hi(v1.z, v1.w, r6, r7);
    lo.x = pack_lo(r0, r1); lo.y = pack_lo(r2, r3);
    lo.z = pack_lo(r4, r5); lo.w = pack_lo(r6, r7);
    int sidx = col * 16 + (c16 ^ (col & 15));
    ((uint4*)wsp)[sidx] = hi;
    ((uint4*)(wsp + 16384))[sidx] = lo;
}

// ---- phase B: per-bin scatter into node buckets; pad buckets to x4 ----
__global__ __launch_bounds__(256) void bin_fill(const int* __restrict__ binc,
                                                const uint2* __restrict__ binbuf,
                                                int* __restrict__ fillc,
                                                unsigned* __restrict__ buck,
                                                int* __restrict__ ovf_cnt,
                                                uint2* __restrict__ ovf) {
    __shared__ int lcnt[256];
    const int tid = threadIdx.x;
    const int bin = blockIdx.x;
    lcnt[tid] = 0;
    __syncthreads();
    int n = binc[bin];
    if (n > BCAP) n = BCAP;
    const uint2* bp = binbuf + (size_t)bin * BCAP;
    for (int i = tid; i < n; i += 256) {
        uint2 q = bp[i];
        int d = (int)q.x;
        int p = atomicAdd(&lcnt[d & 255], 1);
        if (p < CAP) {
            buck[(size_t)d * CAP + p] = q.y;
        } else {
            int o = atomicAdd(ovf_cnt, 1);
            ovf[o] = q;
        }
    }
    __syncthreads();
    int node = bin * 256 + tid;
    if (node < NN) {
        int c = lcnt[tid];
        if (c > CAP) c = CAP;
        int pc = (c + 3) & ~3;                       // pad to multiple of 4
        for (int p = c; p < pc; ++p)
            buck[(size_t)node * CAP + p] = 0;        // src=0, w=+0.0h
        fillc[node] = pc;
    }
}

// ---- aggregate: half-wave per node, uniform 4-edge body, bf16 output ----
// grid 6250 x 256: 8 half-waves/block; lane t owns dims 4t..4t+3
__global__ __launch_bounds__(256) void aggregate(const unsigned* __restrict__ xb,
                                                 const int* __restrict__ fillc,
                                                 const unsigned* __restrict__ buck,
                                                 const int* __restrict__ ovf_cnt,
                                                 const uint2* __restrict__ ovf,
                                                 unsigned* __restrict__ aggb) {
    const int node = blockIdx.x * 8 + (threadIdx.x >> 5);
    const int t = threadIdx.x & 31;
    int cnt = fillc[node];                 // multiple of 4, <= CAP
    if (cnt > CAP) cnt = CAP;
    const uint4* bp4 = (const uint4*)(buck + (size_t)node * CAP);
    const uint2* x2 = (const uint2*)xb;
    float4 acc = {0.f, 0.f, 0.f, 0.f};
    int n4 = cnt >> 2;
    for (int i = 0; i < n4; ++i) {
        uint4 q = bp4[i];
        uint2 u0 = x2[(size_t)(q.x >> 16) * 32 + t];
        uint2 u1 = x2[(size_t)(q.y >> 16) * 32 + t];
        uint2 u2 = x2[(size_t)(q.z >> 16) * 32 + t];
        uint2 u3 = x2[(size_t)(q.w >> 16) * 32 + t];
        float w0 = __half2float(__ushort_as_half((ushort)(q.x & 0xffffu)));
        float w1 = __half2float(__ushort_as_half((ushort)(q.y & 0xffffu)));
        float w2 = __half2float(__ushort_as_half((ushort)(q.z & 0xffffu)));
        float w3 = __half2float(__ushort_as_half((ushort)(q.w & 0xffffu)));
        acc.x += __uint_as_float(u0.x << 16) * w0;
        acc.y += __uint_as_float(u0.x & 0xffff0000u) * w0;
        acc.z += __uint_as_float(u0.y << 16) * w0;
        acc.w += __uint_as_float(u0.y & 0xffff0000u) * w0;
        acc.x += __uint_as_float(u1.x << 16) * w1;
        acc.y += __uint_as_float(u1.x & 0xffff0000u) * w1;
        acc.z += __uint_as_float(u1.y << 16) * w1;
        acc.w += __uint_as_float(u1.y & 0xffff0000u) * w1;
        acc.x += __uint_as_float(u2.x << 16) * w2;
        acc.y += __uint_as_float(u2.x & 0xffff0000u) * w2;
        acc.z += __uint_as_float(u2.y << 16) * w2;
        acc.w += __uint_as_float(u2.y & 0xffff0000u) * w2;
        acc.x += __uint_as_float(u3.x << 16) * w3;
        acc.y += __uint_as_float(u3.x & 0xffff0000u) * w3;
        acc.z += __uint_as_float(u3.y << 16) * w3;
        acc.w += __uint_as_float(u3.y & 0xffff0000u) * w3;
    }
    // overflow entries (statistically never; correctness net)
    int n = *ovf_cnt;
    for (int o = 0; o < n; ++o) {
        uint2 q = ovf[o];
        if ((int)q.x == node) {
            uint2 u = x2[(size_t)(q.y >> 16) * 32 + t];
            float w = __half2float(__ushort_as_half((ushort)(q.y & 0xffffu)));
            acc.x += __uint_as_float(u.x << 16) * w;
            acc.y += __uint_as_float(u.x & 0xffff0000u) * w;
            acc.z += __uint_as_float(u.y << 16) * w;
            acc.w += __uint_as_float(u.y & 0xffff0000u) * w;
        }
    }
    unsigned o0 = f2bf_rne(acc.x) | (f2bf_rne(acc.y) << 16);
    unsigned o1 = f2bf_rne(acc.z) | (f2bf_rne(acc.w) << 16);
    ((uint2*)aggb)[(size_t)node * 32 + t] = make_uint2(o0, o1);
}

// ---- GEMM: bf16 A direct, W hi+lo split (2-term), bias+relu ----
__global__ __launch_bounds__(256) void gemm_mfma(const unsigned* __restrict__ aggb,
                                                 const ushort* __restrict__ wsp,
                                                 const float* __restrict__ bias,
                                                 float* __restrict__ out) {
    __shared__ ushort wl[32768];
    const int tid = threadIdx.x;
    {
        const uint4* s = (const uint4*)wsp;
        uint4* d = (uint4*)wl;
#pragma unroll
        for (int i = 0; i < 16; ++i)
            d[i * 256 + tid] = s[i * 256 + tid];
    }
    __syncthreads();

    const int wid = tid >> 6, lane = tid & 63;
    const int l15 = lane & 15, kg = lane >> 4;
    const int wrbase = blockIdx.x * GBM + wid * 32;

    f32x4 acc[2][8];
    const f32x4 fz = {0.f, 0.f, 0.f, 0.f};
#pragma unroll
    for (int m = 0; m < 2; ++m)
#pragma unroll
        for (int n = 0; n < 8; ++n) acc[m][n] = fz;

    int arow0 = wrbase + l15;
    int arow1 = wrbase + 16 + l15;
    // uint index: 64 uints per row; k-group kg owns bf16 k = kg*8.. -> uint kg*4
    const unsigned* a0p = aggb + (size_t)(arow0 < NN ? arow0 : NN - 1) * 64 + kg * 4;
    const unsigned* a1p = aggb + (size_t)(arow1 < NN ? arow1 : NN - 1) * 64 + kg * 4;

#pragma unroll
    for (int kk = 0; kk < 4; ++kk) {
        uint4 h0 = *(const uint4*)(a0p + kk * 16);   // k = kk*32 + kg*8 + [0..7]
        uint4 h1 = *(const uint4*)(a1p + kk * 16);
        bf16x8 a0 = *(bf16x8*)&h0;
        bf16x8 a1 = *(bf16x8*)&h1;

        int coff = ((kk * 4 + kg) ^ l15) * 8;
#pragma unroll
        for (int nf = 0; nf < 8; ++nf) {
            int bidx = (16 * nf + l15) * 128 + coff;
            bf16x8 bhi = *(const bf16x8*)&wl[bidx];
            bf16x8 blo = *(const bf16x8*)&wl[16384 + bidx];
            acc[0][nf] = __builtin_amdgcn_mfma_f32_16x16x32_bf16(a0, bhi, acc[0][nf], 0, 0, 0);
            acc[1][nf] = __builtin_amdgcn_mfma_f32_16x16x32_bf16(a1, bhi, acc[1][nf], 0, 0, 0);
            acc[0][nf] = __builtin_amdgcn_mfma_f32_16x16x32_bf16(a0, blo, acc[0][nf], 0, 0, 0);
            acc[1][nf] = __builtin_amdgcn_mfma_f32_16x16x32_bf16(a1, blo, acc[1][nf], 0, 0, 0);
        }
    }

    const int rofs = kg * 4;
#pragma unroll
    for (int nf = 0; nf < 8; ++nf) {
        int col = 16 * nf + l15;
        float bv = bias[col];
#pragma unroll
        for (int m = 0; m < 2; ++m) {
#pragma unroll
            for (int r = 0; r < 4; ++r) {
                int row = wrbase + 16 * m + rofs + r;
                if (row < NN) {
                    float h = acc[m][nf][r] + bv;
                    out[(size_t)row * D + col] = h > 0.f ? h : 0.f;
                }
            }
        }
    }
}

extern "C" void kernel_launch(void* const* d_in, const int* in_sizes, int n_in,
                              void* d_out, int out_size, void* d_ws, size_t ws_size,
                              hipStream_t stream) {
    const float* x    = (const float*)d_in[0];
    const int*   eidx = (const int*)d_in[1];   // [2, E] flat: src then dst
    const float* ew   = (const float*)d_in[2];
    const float* W    = (const float*)d_in[3];
    const float* bias = (const float*)d_in[4];
    float* out = (float*)d_out;

    const int* src = eidx;
    const int* dst = eidx + NE;

    // workspace layout (binbuf aliases aggb region: binbuf dead before aggregate writes)
    char* base = (char*)d_ws;
    unsigned* aggb   = (unsigned*)base;                         // NN*D bf16 = 12.8 MB
    uint2*    binbuf = (uint2*)base;                            // 6.4 MB (alias, dead first)
    unsigned* buck   = (unsigned*)(base + 25600000);            // NN*CAP*4 = 12.8 MB
    unsigned* xb     = (unsigned*)(base + 25600000 + 12800000); // 12.8 MB
    ushort*   wsp    = (ushort*)(base + 51200000);              // 64 KB
    int*      fillc   = (int*)(base + 51200000 + 65536);        // 200 KB
    int*      binc    = (int*)(base + 51200000 + 65536 + 200000);
    int*      ovf_cnt = (int*)((char*)binc + NBIN * 4);
    uint2*    ovf     = (uint2*)(base + 51200000 + 65536 + 200000 + 1024); // 512 KB

    hipMemsetAsync(binc, 0, NBIN * 4 + 4, stream);
    mega1<<<MEGA_GRID, 256, 0, stream>>>(x, W, src, dst, ew, xb, wsp, binc, binbuf, ovf_cnt, ovf);
    bin_fill<<<NBIN, 256, 0, stream>>>(binc, binbuf, fillc, buck, ovf_cnt, ovf);
    aggregate<<<6250, 256, 0, stream>>>(xb, fillc, buck, ovf_cnt, ovf, aggb);
    gemm_mfma<<<(NN + GBM - 1) / GBM, 256, 0, stream>>>(aggb, wsp, bias, out);
}